// Round 1
// baseline (808.679 us; speedup 1.0000x reference)
//
#include <hip/hip_runtime.h>
#include <hip/hip_bf16.h>
#include <math.h>

typedef __attribute__((ext_vector_type(8))) __bf16 bf8_t;
typedef __attribute__((ext_vector_type(4))) float f4_t;
typedef __attribute__((ext_vector_type(4))) int   i4_t;

#define XTOK 32768
#define NTOK 40960
#define DIMC 512

// ---------------- weight transpose + cast: WT[n][k] = W[k][n] ----------------
__global__ void transpose_cast(const float* __restrict__ W, __bf16* __restrict__ WT,
                               int K, int N) {
  int idx = blockIdx.x * 256 + threadIdx.x;
  if (idx >= K * N) return;
  int n = idx / K, k = idx - n * K;
  WT[idx] = (__bf16)W[(size_t)k * N + n];
}

// ---------------- token pack: window-order gather + resize, fp32 -> bf16 ----------------
__global__ void pack_tokens(const float* __restrict__ x, const float* __restrict__ y,
                            __bf16* __restrict__ Asrc, __bf16* __restrict__ Aoth,
                            int* __restrict__ srcoff, int* __restrict__ outoff) {
  int g = blockIdx.x;           // window-ordered token row, 0..40959
  int t = threadIdx.x;          // 256 threads, 2 channels each
  int b, h, w; int soff, ooff; bool isx = (g < XTOK);
  if (isx) {
    b = g >> 12;
    int w5 = g & 4095;
    int widx = w5 >> 8, tt = w5 & 255;
    int wh = widx >> 2, ww = widx & 3;
    h = wh * 16 + (tt >> 4); w = ww * 16 + (tt & 15);
    int n = h * 64 + w;
    soff = (b * 4096 + n) * 512;
    ooff = (b * 5120 + n) * 512;
  } else {
    int gy = g - XTOK;
    b = gy >> 10;
    int w5 = gy & 1023;
    int widx = w5 >> 8, tt = w5 & 255;
    int wh = widx >> 1, ww = widx & 1;
    h = wh * 16 + (tt >> 4); w = ww * 16 + (tt & 15);
    int n = h * 32 + w;
    soff = (b * 1024 + n) * 512;
    ooff = (b * 5120 + 4096 + n) * 512;
  }
  if (t == 0) { srcoff[g] = soff; outoff[g] = ooff; }
  const float* sp = (isx ? x : y) + (size_t)soff + t * 2;
  float2 sv = *(const float2*)sp;
  size_t gb = (size_t)g * 512 + t * 2;
  Asrc[gb]     = (__bf16)sv.x;
  Asrc[gb + 1] = (__bf16)sv.y;

  float o0, o1;
  if (isx) {
    // bilinear upsample 32x32 -> 64x64, half-pixel centers, edge clamp
    int h0, h1, w0i, w1i; float fh0, fh1, fw0, fw1;
    if (h & 1) { h0 = h >> 1; h1 = (h0 + 1 < 31) ? h0 + 1 : 31; fh0 = 0.75f; fh1 = 0.25f; }
    else       { h1 = h >> 1; h0 = (h1 - 1 > 0) ? h1 - 1 : 0;   fh0 = 0.25f; fh1 = 0.75f; }
    if (w & 1) { w0i = w >> 1; w1i = (w0i + 1 < 31) ? w0i + 1 : 31; fw0 = 0.75f; fw1 = 0.25f; }
    else       { w1i = w >> 1; w0i = (w1i - 1 > 0) ? w1i - 1 : 0;   fw0 = 0.25f; fw1 = 0.75f; }
    const float* yb = y + (size_t)b * 1024 * 512 + t * 2;
    float2 v00 = *(const float2*)(yb + (h0 * 32 + w0i) * 512);
    float2 v01 = *(const float2*)(yb + (h0 * 32 + w1i) * 512);
    float2 v10 = *(const float2*)(yb + (h1 * 32 + w0i) * 512);
    float2 v11 = *(const float2*)(yb + (h1 * 32 + w1i) * 512);
    o0 = fh0 * (fw0 * v00.x + fw1 * v01.x) + fh1 * (fw0 * v10.x + fw1 * v11.x);
    o1 = fh0 * (fw0 * v00.y + fw1 * v01.y) + fh1 * (fw0 * v10.y + fw1 * v11.y);
  } else {
    // bilinear downsample 64x64 -> 32x32 == 2x2 average pool
    const float* xb = x + (size_t)b * 4096 * 512 + t * 2;
    float2 v00 = *(const float2*)(xb + ((2 * h) * 64 + 2 * w) * 512);
    float2 v01 = *(const float2*)(xb + ((2 * h) * 64 + 2 * w + 1) * 512);
    float2 v10 = *(const float2*)(xb + ((2 * h + 1) * 64 + 2 * w) * 512);
    float2 v11 = *(const float2*)(xb + ((2 * h + 1) * 64 + 2 * w + 1) * 512);
    o0 = 0.25f * (v00.x + v01.x + v10.x + v11.x);
    o1 = 0.25f * (v00.y + v01.y + v10.y + v11.y);
  }
  Aoth[gb]     = (__bf16)o0;
  Aoth[gb + 1] = (__bf16)o1;
}

// ---------------- GEMM: C[M,N] = A[M,K] @ BT[N,K]^T + bias, fused epilogues ----------------
// EPI 0: out bf16 = acc + bias                     (Q,K,V)
// EPI 1: v = acc + bias + residual(src gather); write fp32 toks + bf16 toks
// EPI 2: out bf16 = gelu_exact(acc + bias)         (MLP1)
// EPI 3: v = acc + bias + toksf; write d_out at permuted offset (MLP2)
template<int EPI>
__global__ __launch_bounds__(256, 2)
void gemm_bt(const __bf16* __restrict__ A, const __bf16* __restrict__ BT,
             const float* __restrict__ bias, int K, int row0,
             __bf16* __restrict__ outb, float* __restrict__ outf,
             const float* __restrict__ resx, const float* __restrict__ resy,
             const int* __restrict__ srcoff, const int* __restrict__ outoff,
             const float* __restrict__ toksf, float* __restrict__ dout) {
  const int N = gridDim.y * 128;
  __shared__ __align__(16) __bf16 At[128 * 40];   // +8 bf16 pad: 80B rows, 16B aligned, 2-way banks
  __shared__ __align__(16) __bf16 Bt[128 * 40];
  int tid = threadIdx.x, lane = tid & 63, wid = tid >> 6;
  int m0 = blockIdx.x * 128, n0 = blockIdx.y * 128;
  int wr = wid >> 1, wc = wid & 1;
  int ln15 = lane & 15, kq = lane >> 4;
  f4_t zf = {0.f, 0.f, 0.f, 0.f};
  f4_t acc[4][4];
#pragma unroll
  for (int m = 0; m < 4; ++m)
#pragma unroll
    for (int n = 0; n < 4; ++n) acc[m][n] = zf;

  for (int k0 = 0; k0 < K; k0 += 32) {
    __syncthreads();
#pragma unroll
    for (int r = 0; r < 2; ++r) {
      int cid = tid + r * 256;           // 512 chunks of 16B per tile
      int row = cid >> 2, c8 = (cid & 3) * 8;
      i4_t va = *(const i4_t*)(A + (size_t)(m0 + row) * K + k0 + c8);
      *(i4_t*)&At[row * 40 + c8] = va;
      i4_t vb = *(const i4_t*)(BT + (size_t)(n0 + row) * K + k0 + c8);
      *(i4_t*)&Bt[row * 40 + c8] = vb;
    }
    __syncthreads();
    bf8_t av[4], bv[4];
#pragma unroll
    for (int m = 0; m < 4; ++m) av[m] = *(const bf8_t*)&At[(wr * 64 + m * 16 + ln15) * 40 + kq * 8];
#pragma unroll
    for (int n = 0; n < 4; ++n) bv[n] = *(const bf8_t*)&Bt[(wc * 64 + n * 16 + ln15) * 40 + kq * 8];
#pragma unroll
    for (int m = 0; m < 4; ++m)
#pragma unroll
      for (int n = 0; n < 4; ++n)
        acc[m][n] = __builtin_amdgcn_mfma_f32_16x16x32_bf16(av[m], bv[n], acc[m][n], 0, 0, 0);
  }

  float bs[4];
#pragma unroll
  for (int n = 0; n < 4; ++n) bs[n] = bias[n0 + wc * 64 + n * 16 + ln15];
#pragma unroll
  for (int m = 0; m < 4; ++m) {
    int lrow = m0 + wr * 64 + m * 16 + kq * 4;
#pragma unroll
    for (int r = 0; r < 4; ++r) {
      int grow = row0 + lrow + r;
      int so = 0, oo = 0;
      const float* rptr = nullptr;
      if (EPI == 1) { so = srcoff[grow]; rptr = (grow < XTOK) ? resx : resy; }
      if (EPI == 3) { oo = outoff[grow]; }
#pragma unroll
      for (int n = 0; n < 4; ++n) {
        int gcol = n0 + wc * 64 + n * 16 + ln15;
        float v = acc[m][n][r] + bs[n];
        if (EPI == 0) {
          outb[(size_t)(lrow + r) * N + gcol] = (__bf16)v;
        } else if (EPI == 1) {
          v += rptr[(size_t)so + gcol];
          outf[(size_t)grow * DIMC + gcol] = v;
          outb[(size_t)grow * DIMC + gcol] = (__bf16)v;
        } else if (EPI == 2) {
          float gl = 0.5f * v * (1.0f + erff(v * 0.7071067811865475f));
          outb[(size_t)(lrow + r) * N + gcol] = (__bf16)gl;
        } else {
          v += toksf[(size_t)grow * DIMC + gcol];
          dout[(size_t)oo + gcol] = v;
        }
      }
    }
  }
}

// ---------------- windowed attention: one block per (window, head) ----------------
__global__ __launch_bounds__(256, 1)
void attn_kernel(const __bf16* __restrict__ Qb, const __bf16* __restrict__ Kb,
                 const __bf16* __restrict__ Vb, __bf16* __restrict__ AOb) {
  __shared__ __align__(16) __bf16 Kl[256 * 72];      // [s][64+8]
  __shared__ __align__(16) __bf16 Vt[64 * 264];      // [d][256+8]
  __shared__ __align__(16) __bf16 Pl[4][64 * 72];    // per-wave P tile [64][64+8]
  int tid = threadIdx.x, lane = tid & 63, wid = tid >> 6;
  int ln15 = lane & 15, kq = lane >> 4;
  int win = blockIdx.x >> 3, head = blockIdx.x & 7;
  size_t wtok = (size_t)win * 256;
  int hc = head * 64;

#pragma unroll
  for (int r = 0; r < 8; ++r) {                      // stage K [256][64]
    int cid = tid + r * 256;
    int s = cid >> 3, c8 = (cid & 7) * 8;
    i4_t v = *(const i4_t*)(Kb + (wtok + s) * 512 + hc + c8);
    *(i4_t*)&Kl[s * 72 + c8] = v;
  }
#pragma unroll
  for (int r = 0; r < 8; ++r) {                      // stage V transposed [64][256]
    int cid = tid + r * 256;
    int s = cid >> 3, d0 = (cid & 7) * 8;
    i4_t v = *(const i4_t*)(Vb + (wtok + s) * 512 + hc + d0);
    const __bf16* ve = (const __bf16*)&v;
#pragma unroll
    for (int j = 0; j < 8; ++j) Vt[(d0 + j) * 264 + s] = ve[j];
  }
  __syncthreads();

  bf8_t aq[4][2];
#pragma unroll
  for (int m = 0; m < 4; ++m)
#pragma unroll
    for (int k2 = 0; k2 < 2; ++k2)
      aq[m][k2] = *(const bf8_t*)(Qb + (wtok + wid * 64 + m * 16 + ln15) * 512 + hc + k2 * 32 + kq * 8);

  f4_t zf = {0.f, 0.f, 0.f, 0.f};
  f4_t ao[4][4];
  float mrun[4][4], lrun[4][4];
#pragma unroll
  for (int m = 0; m < 4; ++m)
#pragma unroll
    for (int n = 0; n < 4; ++n) { ao[m][n] = zf; mrun[m][n] = -1e30f; lrun[m][n] = 0.f; }

  __bf16* pw = &Pl[wid][0];
  for (int sb = 0; sb < 4; ++sb) {
    bf8_t kf[4][2];
#pragma unroll
    for (int n = 0; n < 4; ++n)
#pragma unroll
      for (int k2 = 0; k2 < 2; ++k2)
        kf[n][k2] = *(const bf8_t*)&Kl[(sb * 64 + n * 16 + ln15) * 72 + k2 * 32 + kq * 8];
    f4_t s4[4][4];
#pragma unroll
    for (int m = 0; m < 4; ++m)
#pragma unroll
      for (int n = 0; n < 4; ++n) {
        s4[m][n] = zf;
#pragma unroll
        for (int k2 = 0; k2 < 2; ++k2)
          s4[m][n] = __builtin_amdgcn_mfma_f32_16x16x32_bf16(aq[m][k2], kf[n][k2], s4[m][n], 0, 0, 0);
      }
    // online softmax, P -> LDS (bf16)
#pragma unroll
    for (int m = 0; m < 4; ++m) {
#pragma unroll
      for (int r = 0; r < 4; ++r) {
        float bmax = fmaxf(fmaxf(s4[m][0][r], s4[m][1][r]), fmaxf(s4[m][2][r], s4[m][3][r])) * 0.125f;
#pragma unroll
        for (int off = 8; off >= 1; off >>= 1) bmax = fmaxf(bmax, __shfl_xor(bmax, off, 64));
        float mnew = fmaxf(mrun[m][r], bmax);
        float fsc = __expf(mrun[m][r] - mnew);
        mrun[m][r] = mnew;
        float rs = 0.f;
#pragma unroll
        for (int n = 0; n < 4; ++n) {
          float p = __expf(s4[m][n][r] * 0.125f - mnew);
          rs += p;
          pw[(m * 16 + kq * 4 + r) * 72 + n * 16 + ln15] = (__bf16)p;
        }
#pragma unroll
        for (int off = 8; off >= 1; off >>= 1) rs += __shfl_xor(rs, off, 64);
        lrun[m][r] = lrun[m][r] * fsc + rs;
#pragma unroll
        for (int dn = 0; dn < 4; ++dn) ao[m][dn][r] *= fsc;
      }
    }
    // PV
    bf8_t vf[4][2], pf[4][2];
#pragma unroll
    for (int dn = 0; dn < 4; ++dn)
#pragma unroll
      for (int k2 = 0; k2 < 2; ++k2)
        vf[dn][k2] = *(const bf8_t*)&Vt[(dn * 16 + ln15) * 264 + sb * 64 + k2 * 32 + kq * 8];
#pragma unroll
    for (int m = 0; m < 4; ++m)
#pragma unroll
      for (int k2 = 0; k2 < 2; ++k2)
        pf[m][k2] = *(const bf8_t*)&Pl[wid][(m * 16 + ln15) * 72 + k2 * 32 + kq * 8];
#pragma unroll
    for (int m = 0; m < 4; ++m)
#pragma unroll
      for (int dn = 0; dn < 4; ++dn)
#pragma unroll
        for (int k2 = 0; k2 < 2; ++k2)
          ao[m][dn] = __builtin_amdgcn_mfma_f32_16x16x32_bf16(pf[m][k2], vf[dn][k2], ao[m][dn], 0, 0, 0);
  }

#pragma unroll
  for (int m = 0; m < 4; ++m)
#pragma unroll
    for (int r = 0; r < 4; ++r) {
      float inv = 1.f / lrun[m][r];
      size_t row = wtok + wid * 64 + m * 16 + kq * 4 + r;
#pragma unroll
      for (int dn = 0; dn < 4; ++dn)
        AOb[row * 512 + hc + dn * 16 + ln15] = (__bf16)(ao[m][dn][r] * inv);
    }
}

extern "C" void kernel_launch(void* const* d_in, const int* in_sizes, int n_in,
                              void* d_out, int out_size, void* d_ws, size_t ws_size,
                              hipStream_t stream) {
  const float* x  = (const float*)d_in[0];
  const float* y  = (const float*)d_in[1];
  const float* Wq = (const float*)d_in[2];
  const float* bq = (const float*)d_in[3];
  const float* Wk = (const float*)d_in[4];
  const float* bk = (const float*)d_in[5];
  const float* Wv = (const float*)d_in[6];
  const float* bv = (const float*)d_in[7];
  const float* Wo = (const float*)d_in[8];
  const float* bo = (const float*)d_in[9];
  const float* W1 = (const float*)d_in[10];
  const float* b1 = (const float*)d_in[11];
  const float* W2 = (const float*)d_in[12];
  const float* b2 = (const float*)d_in[13];

  char* ws = (char*)d_ws;
  size_t off = 0;
  auto carve = [&](size_t bytes) -> void* {
    void* p = ws + off;
    off += (bytes + 255) & ~(size_t)255;
    return p;
  };
  __bf16* WqT = (__bf16*)carve(512 * 512 * 2);
  __bf16* WkT = (__bf16*)carve(512 * 512 * 2);
  __bf16* WvT = (__bf16*)carve(512 * 512 * 2);
  __bf16* WoT = (__bf16*)carve(512 * 512 * 2);
  __bf16* W1T = (__bf16*)carve(2048 * 512 * 2);
  __bf16* W2T = (__bf16*)carve(512 * 2048 * 2);
  int* srcoff = (int*)carve((size_t)NTOK * 4);
  int* outoff = (int*)carve((size_t)NTOK * 4);
  __bf16* Asrc = (__bf16*)carve((size_t)NTOK * 512 * 2);
  __bf16* Aoth = (__bf16*)carve((size_t)NTOK * 512 * 2);
  __bf16* Qb   = (__bf16*)carve((size_t)NTOK * 512 * 2);
  __bf16* Kb   = (__bf16*)carve((size_t)NTOK * 512 * 2);
  __bf16* Vb   = (__bf16*)carve((size_t)NTOK * 512 * 2);
  // aliases (lifetimes verified: producer of alias runs after last reader of original)
  __bf16* AOb   = Asrc;              // attention out  (Asrc dead after V-GEMM)
  __bf16* toksb = Aoth;              // tokens bf16    (Aoth dead after K-GEMM)
  float*  toksf = (float*)Kb;        // tokens fp32, spans Kb+Vb (dead after attention)
  __bf16* Hb    = Qb;                // MLP hidden chunk (Qb dead after attention)
  float*  dout  = (float*)d_out;

  transpose_cast<<<(512 * 512 + 255) / 256, 256, 0, stream>>>(Wq, WqT, 512, 512);
  transpose_cast<<<(512 * 512 + 255) / 256, 256, 0, stream>>>(Wk, WkT, 512, 512);
  transpose_cast<<<(512 * 512 + 255) / 256, 256, 0, stream>>>(Wv, WvT, 512, 512);
  transpose_cast<<<(512 * 512 + 255) / 256, 256, 0, stream>>>(Wo, WoT, 512, 512);
  transpose_cast<<<(2048 * 512 + 255) / 256, 256, 0, stream>>>(W1, W1T, 512, 2048);
  transpose_cast<<<(2048 * 512 + 255) / 256, 256, 0, stream>>>(W2, W2T, 2048, 512);

  pack_tokens<<<NTOK, 256, 0, stream>>>(x, y, Asrc, Aoth, srcoff, outoff);

  dim3 g1(NTOK / 128, 4);   // N=512
  gemm_bt<0><<<g1, 256, 0, stream>>>(Asrc, WqT, bq, 512, 0, Qb, nullptr, nullptr, nullptr, nullptr, nullptr, nullptr, nullptr);
  gemm_bt<0><<<g1, 256, 0, stream>>>(Aoth, WkT, bk, 512, 0, Kb, nullptr, nullptr, nullptr, nullptr, nullptr, nullptr, nullptr);
  gemm_bt<0><<<g1, 256, 0, stream>>>(Asrc, WvT, bv, 512, 0, Vb, nullptr, nullptr, nullptr, nullptr, nullptr, nullptr, nullptr);

  attn_kernel<<<160 * 8, 256, 0, stream>>>(Qb, Kb, Vb, AOb);

  gemm_bt<1><<<g1, 256, 0, stream>>>(AOb, WoT, bo, 512, 0, toksb, toksf, x, y, srcoff, nullptr, nullptr, nullptr);

  for (int c = 0; c < 4; ++c) {
    int r0 = c * (NTOK / 4);
    dim3 gm1(NTOK / 4 / 128, 16);   // N=2048
    dim3 gm2(NTOK / 4 / 128, 4);    // N=512
    gemm_bt<2><<<gm1, 256, 0, stream>>>(toksb + (size_t)r0 * 512, W1T, b1, 512, r0, Hb, nullptr, nullptr, nullptr, nullptr, nullptr, nullptr, nullptr);
    gemm_bt<3><<<gm2, 256, 0, stream>>>(Hb, W2T, b2, 2048, r0, nullptr, nullptr, nullptr, nullptr, nullptr, outoff, toksf, dout);
  }
}

// Round 2
// 788.508 us; speedup vs baseline: 1.0256x; 1.0256x over previous
//
#include <hip/hip_runtime.h>
#include <hip/hip_bf16.h>
#include <math.h>

typedef __attribute__((ext_vector_type(8))) __bf16 bf8_t;
typedef __attribute__((ext_vector_type(4))) float f4_t;
typedef __attribute__((ext_vector_type(4))) int   i4_t;

#define XTOK 32768
#define NTOK 40960
#define DIMC 512

__device__ __forceinline__ void gload_lds16(const __bf16* g, __bf16* l) {
  __builtin_amdgcn_global_load_lds((const __attribute__((address_space(1))) void*)g,
                                   (__attribute__((address_space(3))) void*)l, 16, 0, 0);
}

// ---------------- weight transpose + cast (LDS-tiled): WT[n][k] = W[k][n] ----------------
__global__ void transpose_cast(const float* __restrict__ W, __bf16* __restrict__ WT,
                               int K, int N) {
  __shared__ float t[32][33];
  int bn = blockIdx.x * 32, bk = blockIdx.y * 32;
  int tx = threadIdx.x & 31, ty = threadIdx.x >> 5;   // 32 x 8
#pragma unroll
  for (int i = 0; i < 4; ++i)
    t[ty + i * 8][tx] = W[(size_t)(bk + ty + i * 8) * N + bn + tx];
  __syncthreads();
#pragma unroll
  for (int i = 0; i < 4; ++i)
    WT[(size_t)(bn + ty + i * 8) * K + bk + tx] = (__bf16)t[tx][ty + i * 8];
}

// ---------------- token pack: window-order gather + resize, fp32 -> bf16 ----------------
__global__ void pack_tokens(const float* __restrict__ x, const float* __restrict__ y,
                            __bf16* __restrict__ Asrc, __bf16* __restrict__ Aoth,
                            int* __restrict__ srcoff, int* __restrict__ outoff) {
  int g = blockIdx.x;           // window-ordered token row, 0..40959
  int t = threadIdx.x;          // 256 threads, 2 channels each
  int b, h, w; int soff, ooff; bool isx = (g < XTOK);
  if (isx) {
    b = g >> 12;
    int w5 = g & 4095;
    int widx = w5 >> 8, tt = w5 & 255;
    int wh = widx >> 2, ww = widx & 3;
    h = wh * 16 + (tt >> 4); w = ww * 16 + (tt & 15);
    int n = h * 64 + w;
    soff = (b * 4096 + n) * 512;
    ooff = (b * 5120 + n) * 512;
  } else {
    int gy = g - XTOK;
    b = gy >> 10;
    int w5 = gy & 1023;
    int widx = w5 >> 8, tt = w5 & 255;
    int wh = widx >> 1, ww = widx & 1;
    h = wh * 16 + (tt >> 4); w = ww * 16 + (tt & 15);
    int n = h * 32 + w;
    soff = (b * 1024 + n) * 512;
    ooff = (b * 5120 + 4096 + n) * 512;
  }
  if (t == 0) { srcoff[g] = soff; outoff[g] = ooff; }
  const float* sp = (isx ? x : y) + (size_t)soff + t * 2;
  float2 sv = *(const float2*)sp;
  size_t gb = (size_t)g * 512 + t * 2;
  Asrc[gb]     = (__bf16)sv.x;
  Asrc[gb + 1] = (__bf16)sv.y;

  float o0, o1;
  if (isx) {
    // bilinear upsample 32x32 -> 64x64, half-pixel centers, edge clamp
    int h0, h1, w0i, w1i; float fh0, fh1, fw0, fw1;
    if (h & 1) { h0 = h >> 1; h1 = (h0 + 1 < 31) ? h0 + 1 : 31; fh0 = 0.75f; fh1 = 0.25f; }
    else       { h1 = h >> 1; h0 = (h1 - 1 > 0) ? h1 - 1 : 0;   fh0 = 0.25f; fh1 = 0.75f; }
    if (w & 1) { w0i = w >> 1; w1i = (w0i + 1 < 31) ? w0i + 1 : 31; fw0 = 0.75f; fw1 = 0.25f; }
    else       { w1i = w >> 1; w0i = (w1i - 1 > 0) ? w1i - 1 : 0;   fw0 = 0.25f; fw1 = 0.75f; }
    const float* yb = y + (size_t)b * 1024 * 512 + t * 2;
    float2 v00 = *(const float2*)(yb + (h0 * 32 + w0i) * 512);
    float2 v01 = *(const float2*)(yb + (h0 * 32 + w1i) * 512);
    float2 v10 = *(const float2*)(yb + (h1 * 32 + w0i) * 512);
    float2 v11 = *(const float2*)(yb + (h1 * 32 + w1i) * 512);
    o0 = fh0 * (fw0 * v00.x + fw1 * v01.x) + fh1 * (fw0 * v10.x + fw1 * v11.x);
    o1 = fh0 * (fw0 * v00.y + fw1 * v01.y) + fh1 * (fw0 * v10.y + fw1 * v11.y);
  } else {
    // bilinear downsample 64x64 -> 32x32 == 2x2 average pool
    const float* xb = x + (size_t)b * 4096 * 512 + t * 2;
    float2 v00 = *(const float2*)(xb + ((2 * h) * 64 + 2 * w) * 512);
    float2 v01 = *(const float2*)(xb + ((2 * h) * 64 + 2 * w + 1) * 512);
    float2 v10 = *(const float2*)(xb + ((2 * h + 1) * 64 + 2 * w) * 512);
    float2 v11 = *(const float2*)(xb + ((2 * h + 1) * 64 + 2 * w + 1) * 512);
    o0 = 0.25f * (v00.x + v01.x + v10.x + v11.x);
    o1 = 0.25f * (v00.y + v01.y + v10.y + v11.y);
  }
  Aoth[gb]     = (__bf16)o0;
  Aoth[gb + 1] = (__bf16)o1;
}

// ---------------- GEMM (m97 structure): C[M,N] = A[M,K] @ BT[N,K]^T + bias ----------------
// Linear LDS [128][32], global_load_lds width=16, 2 barriers per K-step.
// EPI 0: out bf16 = acc + bias                     (Q,K,V)
// EPI 1: v = acc + bias + residual(src gather); write fp32 toks + bf16 toks
// EPI 2: out bf16 = gelu_exact(acc + bias)         (MLP1)
// EPI 3: v = acc + bias + toksf; write d_out at permuted offset (MLP2)
template<int EPI>
__global__ __launch_bounds__(256, 2)
void gemm_bt(const __bf16* __restrict__ A, const __bf16* __restrict__ BT,
             const float* __restrict__ bias, int K, int row0,
             __bf16* __restrict__ outb, float* __restrict__ outf,
             const float* __restrict__ resx, const float* __restrict__ resy,
             const int* __restrict__ srcoff, const int* __restrict__ outoff,
             const float* __restrict__ toksf, float* __restrict__ dout) {
  const int N = gridDim.y * 128;
  __shared__ __align__(16) __bf16 At[128 * 32];
  __shared__ __align__(16) __bf16 Bt[128 * 32];
  int tid = threadIdx.x, lane = tid & 63, wid = tid >> 6;
  int m0 = blockIdx.x * 128, n0 = blockIdx.y * 128;
  int wr = wid >> 1, wc = wid & 1;
  int ln15 = lane & 15, kq = lane >> 4;
  int lrow = lane >> 2, lc8 = (lane & 3) * 8;        // staging lane map: 16 rows x 4 chunks
  f4_t zf = {0.f, 0.f, 0.f, 0.f};
  f4_t acc[4][4];
#pragma unroll
  for (int m = 0; m < 4; ++m)
#pragma unroll
    for (int n = 0; n < 4; ++n) acc[m][n] = zf;

  for (int k0 = 0; k0 < K; k0 += 32) {
    __syncthreads();
#pragma unroll
    for (int i = 0; i < 2; ++i) {                    // each wave stages 32 rows of A and B
      int r0 = (wid * 2 + i) * 16;
      gload_lds16(A  + (size_t)(m0 + r0 + lrow) * K + k0 + lc8, &At[r0 * 32]);
      gload_lds16(BT + (size_t)(n0 + r0 + lrow) * K + k0 + lc8, &Bt[r0 * 32]);
    }
    __syncthreads();                                  // drains vmcnt before any wave proceeds
    bf8_t av[4], bv[4];
#pragma unroll
    for (int m = 0; m < 4; ++m) av[m] = *(const bf8_t*)&At[(wr * 64 + m * 16 + ln15) * 32 + kq * 8];
#pragma unroll
    for (int n = 0; n < 4; ++n) bv[n] = *(const bf8_t*)&Bt[(wc * 64 + n * 16 + ln15) * 32 + kq * 8];
#pragma unroll
    for (int m = 0; m < 4; ++m)
#pragma unroll
      for (int n = 0; n < 4; ++n)
        acc[m][n] = __builtin_amdgcn_mfma_f32_16x16x32_bf16(av[m], bv[n], acc[m][n], 0, 0, 0);
  }

  float bs[4];
#pragma unroll
  for (int n = 0; n < 4; ++n) bs[n] = bias[n0 + wc * 64 + n * 16 + ln15];
#pragma unroll
  for (int m = 0; m < 4; ++m) {
    int lrow2 = m0 + wr * 64 + m * 16 + kq * 4;
#pragma unroll
    for (int r = 0; r < 4; ++r) {
      int grow = row0 + lrow2 + r;
      int so = 0, oo = 0;
      const float* rptr = nullptr;
      if (EPI == 1) { so = srcoff[grow]; rptr = (grow < XTOK) ? resx : resy; }
      if (EPI == 3) { oo = outoff[grow]; }
#pragma unroll
      for (int n = 0; n < 4; ++n) {
        int gcol = n0 + wc * 64 + n * 16 + ln15;
        float v = acc[m][n][r] + bs[n];
        if (EPI == 0) {
          outb[(size_t)(lrow2 + r) * N + gcol] = (__bf16)v;
        } else if (EPI == 1) {
          v += rptr[(size_t)so + gcol];
          outf[(size_t)grow * DIMC + gcol] = v;
          outb[(size_t)grow * DIMC + gcol] = (__bf16)v;
        } else if (EPI == 2) {
          float gl = 0.5f * v * (1.0f + erff(v * 0.7071067811865475f));
          outb[(size_t)(lrow2 + r) * N + gcol] = (__bf16)gl;
        } else {
          v += toksf[(size_t)grow * DIMC + gcol];
          dout[(size_t)oo + gcol] = v;
        }
      }
    }
  }
}

// ---------------- windowed attention v2: K/Q from L2, swizzled V + P LDS ----------------
// LDS 64KB -> 2 blocks/CU. All LDS accesses <=2-way banked via XOR chunk swizzle.
__global__ __launch_bounds__(256, 2)
void attn_kernel(const __bf16* __restrict__ Qb, const __bf16* __restrict__ Kb,
                 const __bf16* __restrict__ Vb, __bf16* __restrict__ AOb) {
  __shared__ __align__(16) __bf16 Vt[64 * 256];      // [d][s], el = d*256 + (((s>>3)^(d&7))<<3 | (s&7))
  __shared__ __align__(16) __bf16 Pl[4][64 * 64];    // per-wave [q][s], el = q*64 + (((s>>3)^(q&7))<<3 | (s&7))
  int tid = threadIdx.x, lane = tid & 63, wid = tid >> 6;
  int ln15 = lane & 15, kq = lane >> 4;
  int win = blockIdx.x >> 3, head = blockIdx.x & 7;
  size_t wtok = (size_t)win * 256;
  int hc = head * 64;

  // stage V: coalesced-ish 16B global loads, conflict-free swizzled scatter to LDS
#pragma unroll
  for (int it = 0; it < 8; ++it) {
    int cid = tid + it * 256;
    int s = cid & 255, d0 = (cid >> 8) * 8;
    i4_t v = *(const i4_t*)(Vb + (wtok + s) * 512 + hc + d0);
    const __bf16* ve = (const __bf16*)&v;
#pragma unroll
    for (int j = 0; j < 8; ++j) {
      int d = d0 + j;
      Vt[d * 256 + ((((s >> 3) ^ (d & 7)) << 3) | (s & 7))] = ve[j];
    }
  }

  // Q fragments straight from global (L2-resident)
  bf8_t aq[4][2];
#pragma unroll
  for (int m = 0; m < 4; ++m)
#pragma unroll
    for (int k2 = 0; k2 < 2; ++k2)
      aq[m][k2] = *(const bf8_t*)(Qb + (wtok + wid * 64 + m * 16 + ln15) * 512 + hc + k2 * 32 + kq * 8);

  __syncthreads();

  f4_t zf = {0.f, 0.f, 0.f, 0.f};
  f4_t ao[4][4];
  float mrun[4][4], lrun[4][4];
#pragma unroll
  for (int m = 0; m < 4; ++m)
#pragma unroll
    for (int n = 0; n < 4; ++n) { ao[m][n] = zf; mrun[m][n] = -1e30f; lrun[m][n] = 0.f; }

  __bf16* pw = &Pl[wid][0];
  for (int sb = 0; sb < 4; ++sb) {
    // K fragments straight from global (L2-resident, shared across the window's 8 heads)
    bf8_t kf[4][2];
#pragma unroll
    for (int n = 0; n < 4; ++n)
#pragma unroll
      for (int k2 = 0; k2 < 2; ++k2)
        kf[n][k2] = *(const bf8_t*)(Kb + (wtok + sb * 64 + n * 16 + ln15) * 512 + hc + k2 * 32 + kq * 8);
    f4_t s4[4][4];
#pragma unroll
    for (int m = 0; m < 4; ++m)
#pragma unroll
      for (int n = 0; n < 4; ++n) {
        s4[m][n] = zf;
#pragma unroll
        for (int k2 = 0; k2 < 2; ++k2)
          s4[m][n] = __builtin_amdgcn_mfma_f32_16x16x32_bf16(aq[m][k2], kf[n][k2], s4[m][n], 0, 0, 0);
      }
    // online softmax, P -> swizzled per-wave LDS (bf16)
#pragma unroll
    for (int m = 0; m < 4; ++m) {
#pragma unroll
      for (int r = 0; r < 4; ++r) {
        int q = m * 16 + kq * 4 + r;
        float bmax = fmaxf(fmaxf(s4[m][0][r], s4[m][1][r]), fmaxf(s4[m][2][r], s4[m][3][r])) * 0.125f;
#pragma unroll
        for (int off = 8; off >= 1; off >>= 1) bmax = fmaxf(bmax, __shfl_xor(bmax, off, 64));
        float mnew = fmaxf(mrun[m][r], bmax);
        float fsc = __expf(mrun[m][r] - mnew);
        mrun[m][r] = mnew;
        float rs = 0.f;
#pragma unroll
        for (int n = 0; n < 4; ++n) {
          int s = n * 16 + ln15;
          float p = __expf(s4[m][n][r] * 0.125f - mnew);
          rs += p;
          pw[q * 64 + ((((s >> 3) ^ (q & 7)) << 3) | (s & 7))] = (__bf16)p;
        }
#pragma unroll
        for (int off = 8; off >= 1; off >>= 1) rs += __shfl_xor(rs, off, 64);
        lrun[m][r] = lrun[m][r] * fsc + rs;
#pragma unroll
        for (int dn = 0; dn < 4; ++dn) ao[m][dn][r] *= fsc;
      }
    }
    // PV
    bf8_t vf[4][2], pf[4][2];
#pragma unroll
    for (int dn = 0; dn < 4; ++dn)
#pragma unroll
      for (int k2 = 0; k2 < 2; ++k2) {
        int d = dn * 16 + ln15;
        vf[dn][k2] = *(const bf8_t*)&Vt[d * 256 + (((sb * 8 + k2 * 4 + kq) ^ (d & 7)) << 3)];
      }
#pragma unroll
    for (int m = 0; m < 4; ++m)
#pragma unroll
      for (int k2 = 0; k2 < 2; ++k2) {
        int q = m * 16 + ln15;
        pf[m][k2] = *(const bf8_t*)&pw[q * 64 + ((((k2 * 4 + kq) ^ (q & 7))) << 3)];
      }
#pragma unroll
    for (int m = 0; m < 4; ++m)
#pragma unroll
      for (int dn = 0; dn < 4; ++dn)
#pragma unroll
        for (int k2 = 0; k2 < 2; ++k2)
          ao[m][dn] = __builtin_amdgcn_mfma_f32_16x16x32_bf16(pf[m][k2], vf[dn][k2], ao[m][dn], 0, 0, 0);
  }

#pragma unroll
  for (int m = 0; m < 4; ++m)
#pragma unroll
    for (int r = 0; r < 4; ++r) {
      float inv = 1.f / lrun[m][r];
      size_t row = wtok + wid * 64 + m * 16 + kq * 4 + r;
#pragma unroll
      for (int dn = 0; dn < 4; ++dn)
        AOb[row * 512 + hc + dn * 16 + ln15] = (__bf16)(ao[m][dn][r] * inv);
    }
}

extern "C" void kernel_launch(void* const* d_in, const int* in_sizes, int n_in,
                              void* d_out, int out_size, void* d_ws, size_t ws_size,
                              hipStream_t stream) {
  const float* x  = (const float*)d_in[0];
  const float* y  = (const float*)d_in[1];
  const float* Wq = (const float*)d_in[2];
  const float* bq = (const float*)d_in[3];
  const float* Wk = (const float*)d_in[4];
  const float* bk = (const float*)d_in[5];
  const float* Wv = (const float*)d_in[6];
  const float* bv = (const float*)d_in[7];
  const float* Wo = (const float*)d_in[8];
  const float* bo = (const float*)d_in[9];
  const float* W1 = (const float*)d_in[10];
  const float* b1 = (const float*)d_in[11];
  const float* W2 = (const float*)d_in[12];
  const float* b2 = (const float*)d_in[13];

  char* ws = (char*)d_ws;
  size_t off = 0;
  auto carve = [&](size_t bytes) -> void* {
    void* p = ws + off;
    off += (bytes + 255) & ~(size_t)255;
    return p;
  };
  __bf16* WqT = (__bf16*)carve(512 * 512 * 2);
  __bf16* WkT = (__bf16*)carve(512 * 512 * 2);
  __bf16* WvT = (__bf16*)carve(512 * 512 * 2);
  __bf16* WoT = (__bf16*)carve(512 * 512 * 2);
  __bf16* W1T = (__bf16*)carve(2048 * 512 * 2);
  __bf16* W2T = (__bf16*)carve(512 * 2048 * 2);
  int* srcoff = (int*)carve((size_t)NTOK * 4);
  int* outoff = (int*)carve((size_t)NTOK * 4);
  __bf16* Asrc = (__bf16*)carve((size_t)NTOK * 512 * 2);
  __bf16* Aoth = (__bf16*)carve((size_t)NTOK * 512 * 2);
  __bf16* Qb   = (__bf16*)carve((size_t)NTOK * 512 * 2);
  __bf16* Kb   = (__bf16*)carve((size_t)NTOK * 512 * 2);
  __bf16* Vb   = (__bf16*)carve((size_t)NTOK * 512 * 2);
  // aliases (lifetimes verified: producer of alias runs after last reader of original)
  __bf16* AOb   = Asrc;              // attention out  (Asrc dead after V-GEMM)
  __bf16* toksb = Aoth;              // tokens bf16    (Aoth dead after K-GEMM)
  float*  toksf = (float*)Kb;        // tokens fp32, spans Kb+Vb (dead after attention)
  __bf16* Hb    = Qb;                // MLP hidden chunk (Qb dead after attention)
  float*  dout  = (float*)d_out;

  dim3 tb(256);
  transpose_cast<<<dim3(512 / 32, 512 / 32), tb, 0, stream>>>(Wq, WqT, 512, 512);
  transpose_cast<<<dim3(512 / 32, 512 / 32), tb, 0, stream>>>(Wk, WkT, 512, 512);
  transpose_cast<<<dim3(512 / 32, 512 / 32), tb, 0, stream>>>(Wv, WvT, 512, 512);
  transpose_cast<<<dim3(512 / 32, 512 / 32), tb, 0, stream>>>(Wo, WoT, 512, 512);
  transpose_cast<<<dim3(2048 / 32, 512 / 32), tb, 0, stream>>>(W1, W1T, 512, 2048);
  transpose_cast<<<dim3(512 / 32, 2048 / 32), tb, 0, stream>>>(W2, W2T, 2048, 512);

  pack_tokens<<<NTOK, 256, 0, stream>>>(x, y, Asrc, Aoth, srcoff, outoff);

  dim3 g1(NTOK / 128, 4);   // N=512
  gemm_bt<0><<<g1, 256, 0, stream>>>(Asrc, WqT, bq, 512, 0, Qb, nullptr, nullptr, nullptr, nullptr, nullptr, nullptr, nullptr);
  gemm_bt<0><<<g1, 256, 0, stream>>>(Aoth, WkT, bk, 512, 0, Kb, nullptr, nullptr, nullptr, nullptr, nullptr, nullptr, nullptr);
  gemm_bt<0><<<g1, 256, 0, stream>>>(Asrc, WvT, bv, 512, 0, Vb, nullptr, nullptr, nullptr, nullptr, nullptr, nullptr, nullptr);

  attn_kernel<<<160 * 8, 256, 0, stream>>>(Qb, Kb, Vb, AOb);

  gemm_bt<1><<<g1, 256, 0, stream>>>(AOb, WoT, bo, 512, 0, toksb, toksf, x, y, srcoff, nullptr, nullptr, nullptr);

  for (int c = 0; c < 4; ++c) {
    int r0 = c * (NTOK / 4);
    dim3 gm1(NTOK / 4 / 128, 16);   // N=2048
    dim3 gm2(NTOK / 4 / 128, 4);    // N=512
    gemm_bt<2><<<gm1, 256, 0, stream>>>(toksb + (size_t)r0 * 512, W1T, b1, 512, r0, Hb, nullptr, nullptr, nullptr, nullptr, nullptr, nullptr, nullptr);
    gemm_bt<3><<<gm2, 256, 0, stream>>>(Hb, W2T, b2, 2048, r0, nullptr, nullptr, nullptr, nullptr, nullptr, outoff, toksf, dout);
  }
}

// Round 3
// 660.632 us; speedup vs baseline: 1.2241x; 1.1936x over previous
//
#include <hip/hip_runtime.h>
#include <hip/hip_bf16.h>
#include <math.h>

typedef __attribute__((ext_vector_type(8))) __bf16 bf8_t;
typedef __attribute__((ext_vector_type(4))) float f4_t;
typedef __attribute__((ext_vector_type(4))) int   i4_t;

#define XTOK 32768
#define NTOK 40960
#define DIMC 512

__device__ __forceinline__ void gload_lds16(const __bf16* g, __bf16* l) {
  __builtin_amdgcn_global_load_lds((const __attribute__((address_space(1))) void*)g,
                                   (__attribute__((address_space(3))) void*)l, 16, 0, 0);
}

// ---------------- weight transpose + cast (LDS-tiled): WT[n][k] = W[k][n] ----------------
__global__ void transpose_cast(const float* __restrict__ W, __bf16* __restrict__ WT,
                               int K, int N) {
  __shared__ float t[32][33];
  int bn = blockIdx.x * 32, bk = blockIdx.y * 32;
  int tx = threadIdx.x & 31, ty = threadIdx.x >> 5;   // 32 x 8
#pragma unroll
  for (int i = 0; i < 4; ++i)
    t[ty + i * 8][tx] = W[(size_t)(bk + ty + i * 8) * N + bn + tx];
  __syncthreads();
#pragma unroll
  for (int i = 0; i < 4; ++i)
    WT[(size_t)(bn + ty + i * 8) * K + bk + tx] = (__bf16)t[tx][ty + i * 8];
}

// ---------------- token pack: window-order gather + resize, fp32 -> bf16 ----------------
__global__ void pack_tokens(const float* __restrict__ x, const float* __restrict__ y,
                            __bf16* __restrict__ Asrc, __bf16* __restrict__ Aoth,
                            int* __restrict__ srcoff, int* __restrict__ outoff) {
  int g = blockIdx.x;           // window-ordered token row, 0..40959
  int t = threadIdx.x;          // 256 threads, 2 channels each
  int b, h, w; int soff, ooff; bool isx = (g < XTOK);
  if (isx) {
    b = g >> 12;
    int w5 = g & 4095;
    int widx = w5 >> 8, tt = w5 & 255;
    int wh = widx >> 2, ww = widx & 3;
    h = wh * 16 + (tt >> 4); w = ww * 16 + (tt & 15);
    int n = h * 64 + w;
    soff = (b * 4096 + n) * 512;
    ooff = (b * 5120 + n) * 512;
  } else {
    int gy = g - XTOK;
    b = gy >> 10;
    int w5 = gy & 1023;
    int widx = w5 >> 8, tt = w5 & 255;
    int wh = widx >> 1, ww = widx & 1;
    h = wh * 16 + (tt >> 4); w = ww * 16 + (tt & 15);
    int n = h * 32 + w;
    soff = (b * 1024 + n) * 512;
    ooff = (b * 5120 + 4096 + n) * 512;
  }
  if (t == 0) { srcoff[g] = soff; outoff[g] = ooff; }
  const float* sp = (isx ? x : y) + (size_t)soff + t * 2;
  float2 sv = *(const float2*)sp;
  size_t gb = (size_t)g * 512 + t * 2;
  Asrc[gb]     = (__bf16)sv.x;
  Asrc[gb + 1] = (__bf16)sv.y;

  float o0, o1;
  if (isx) {
    // bilinear upsample 32x32 -> 64x64, half-pixel centers, edge clamp
    int h0, h1, w0i, w1i; float fh0, fh1, fw0, fw1;
    if (h & 1) { h0 = h >> 1; h1 = (h0 + 1 < 31) ? h0 + 1 : 31; fh0 = 0.75f; fh1 = 0.25f; }
    else       { h1 = h >> 1; h0 = (h1 - 1 > 0) ? h1 - 1 : 0;   fh0 = 0.25f; fh1 = 0.75f; }
    if (w & 1) { w0i = w >> 1; w1i = (w0i + 1 < 31) ? w0i + 1 : 31; fw0 = 0.75f; fw1 = 0.25f; }
    else       { w1i = w >> 1; w0i = (w1i - 1 > 0) ? w1i - 1 : 0;   fw0 = 0.25f; fw1 = 0.75f; }
    const float* yb = y + (size_t)b * 1024 * 512 + t * 2;
    float2 v00 = *(const float2*)(yb + (h0 * 32 + w0i) * 512);
    float2 v01 = *(const float2*)(yb + (h0 * 32 + w1i) * 512);
    float2 v10 = *(const float2*)(yb + (h1 * 32 + w0i) * 512);
    float2 v11 = *(const float2*)(yb + (h1 * 32 + w1i) * 512);
    o0 = fh0 * (fw0 * v00.x + fw1 * v01.x) + fh1 * (fw0 * v10.x + fw1 * v11.x);
    o1 = fh0 * (fw0 * v00.y + fw1 * v01.y) + fh1 * (fw0 * v10.y + fw1 * v11.y);
  } else {
    // bilinear downsample 64x64 -> 32x32 == 2x2 average pool
    const float* xb = x + (size_t)b * 4096 * 512 + t * 2;
    float2 v00 = *(const float2*)(xb + ((2 * h) * 64 + 2 * w) * 512);
    float2 v01 = *(const float2*)(xb + ((2 * h) * 64 + 2 * w + 1) * 512);
    float2 v10 = *(const float2*)(xb + ((2 * h + 1) * 64 + 2 * w) * 512);
    float2 v11 = *(const float2*)(xb + ((2 * h + 1) * 64 + 2 * w + 1) * 512);
    o0 = 0.25f * (v00.x + v01.x + v10.x + v11.x);
    o1 = 0.25f * (v00.y + v01.y + v10.y + v11.y);
  }
  Aoth[gb]     = (__bf16)o0;
  Aoth[gb + 1] = (__bf16)o1;
}

// ---------------- GEMM (m97 structure): C[M,N] = A[M,K] @ BT[N,K]^T + bias ----------------
// EPI 0: out bf16 = acc + bias                     (K-proj)
// EPI 1: v = acc + bias + residual(src gather); write fp32 toks + bf16 toks   (Wo)
// EPI 2: out bf16 = gelu_exact(acc + bias)         (MLP1)
// EPI 3: v = acc + bias + toksf; write d_out at permuted offset (MLP2)
// EPI 4: fused QV: n0<512 -> outb (Q, bias), else outb2 (V, bias2)
template<int EPI>
__global__ __launch_bounds__(256, 2)
void gemm_bt(const __bf16* __restrict__ A, const __bf16* __restrict__ BT,
             const float* __restrict__ bias, const float* __restrict__ bias2,
             int K, int row0,
             __bf16* __restrict__ outb, __bf16* __restrict__ outb2,
             float* __restrict__ outf,
             const float* __restrict__ resx, const float* __restrict__ resy,
             const int* __restrict__ srcoff, const int* __restrict__ outoff,
             const float* __restrict__ toksf, float* __restrict__ dout) {
  const int N = gridDim.y * 128;
  __shared__ __align__(16) __bf16 At[128 * 32];
  __shared__ __align__(16) __bf16 Bt[128 * 32];
  int tid = threadIdx.x, lane = tid & 63, wid = tid >> 6;
  int m0 = blockIdx.x * 128, n0 = blockIdx.y * 128;
  int wr = wid >> 1, wc = wid & 1;
  int ln15 = lane & 15, kq = lane >> 4;
  int lrow = lane >> 2, lc8 = (lane & 3) * 8;        // staging lane map: 16 rows x 4 chunks
  f4_t zf = {0.f, 0.f, 0.f, 0.f};
  f4_t acc[4][4];
#pragma unroll
  for (int m = 0; m < 4; ++m)
#pragma unroll
    for (int n = 0; n < 4; ++n) acc[m][n] = zf;

  for (int k0 = 0; k0 < K; k0 += 32) {
    __syncthreads();
#pragma unroll
    for (int i = 0; i < 2; ++i) {                    // each wave stages 32 rows of A and B
      int r0 = (wid * 2 + i) * 16;
      gload_lds16(A  + (size_t)(m0 + r0 + lrow) * K + k0 + lc8, &At[r0 * 32]);
      gload_lds16(BT + (size_t)(n0 + r0 + lrow) * K + k0 + lc8, &Bt[r0 * 32]);
    }
    __syncthreads();
    bf8_t av[4], bv[4];
#pragma unroll
    for (int m = 0; m < 4; ++m) av[m] = *(const bf8_t*)&At[(wr * 64 + m * 16 + ln15) * 32 + kq * 8];
#pragma unroll
    for (int n = 0; n < 4; ++n) bv[n] = *(const bf8_t*)&Bt[(wc * 64 + n * 16 + ln15) * 32 + kq * 8];
#pragma unroll
    for (int m = 0; m < 4; ++m)
#pragma unroll
      for (int n = 0; n < 4; ++n)
        acc[m][n] = __builtin_amdgcn_mfma_f32_16x16x32_bf16(av[m], bv[n], acc[m][n], 0, 0, 0);
  }

  bool hi = (EPI == 4) && (n0 >= 512);
  const float* bptr = hi ? bias2 : bias;
  int nbase = hi ? n0 - 512 : n0;
  float bs[4];
#pragma unroll
  for (int n = 0; n < 4; ++n) bs[n] = bptr[nbase + wc * 64 + n * 16 + ln15];
#pragma unroll
  for (int m = 0; m < 4; ++m) {
    int lrow2 = m0 + wr * 64 + m * 16 + kq * 4;
#pragma unroll
    for (int r = 0; r < 4; ++r) {
      int grow = row0 + lrow2 + r;
      int so = 0, oo = 0;
      const float* rptr = nullptr;
      if (EPI == 1) { so = srcoff[grow]; rptr = (grow < XTOK) ? resx : resy; }
      if (EPI == 3) { oo = outoff[grow]; }
#pragma unroll
      for (int n = 0; n < 4; ++n) {
        int gcol = nbase + wc * 64 + n * 16 + ln15;
        float v = acc[m][n][r] + bs[n];
        if (EPI == 0) {
          outb[(size_t)(lrow2 + r) * 512 + gcol] = (__bf16)v;
        } else if (EPI == 4) {
          __bf16* wb = hi ? outb2 : outb;
          wb[(size_t)(lrow2 + r) * 512 + gcol] = (__bf16)v;
        } else if (EPI == 1) {
          v += rptr[(size_t)so + gcol];
          outf[(size_t)grow * DIMC + gcol] = v;
          outb[(size_t)grow * DIMC + gcol] = (__bf16)v;
        } else if (EPI == 2) {
          float gl = 0.5f * v * (1.0f + erff(v * 0.7071067811865475f));
          outb[(size_t)(lrow2 + r) * N + gcol] = (__bf16)gl;
        } else {
          v += toksf[(size_t)grow * DIMC + gcol];
          dout[(size_t)oo + gcol] = v;
        }
      }
    }
  }
}

// ---------------- windowed attention v3: swapped-QK in-lane softmax ----------------
// 512 threads / 8 waves, wave w handles queries [w*32, w*32+32) as 2 q-tiles of 16.
// S^T = mfma(K_frag, Q_frag): lane owns one query column -> full row softmax in-lane,
// only 4 shuffles per q-tile. K in LDS (pre-swizzled global_load_lds), V transposed
// swizzled, P per-wave swizzled LDS (b64 ops). Normalization folded into P.
__global__ __launch_bounds__(512, 1)
void attn_kernel(const __bf16* __restrict__ Qb, const __bf16* __restrict__ Kb,
                 const __bf16* __restrict__ Vb, __bf16* __restrict__ AOb) {
  __shared__ __align__(16) __bf16 Kl[256 * 64];      // chunk16 i = s*8 + (c ^ (s&7))
  __shared__ __align__(16) __bf16 Vt[64 * 256];      // [d][s], chunk8(s>>3) ^ (d&7)
  __shared__ __align__(16) __bf16 Pl[8][16 * 256];   // per-wave [q][s], chunk8 c^=q
  int tid = threadIdx.x, lane = tid & 63, wid = tid >> 6;
  int l15 = lane & 15, kq = lane >> 4;
  int win = blockIdx.x >> 3, head = blockIdx.x & 7;
  size_t wtok = (size_t)win * 256;
  int hc = head * 64;

  // ---- stage K: 2048 x 16B chunks via global_load_lds, source pre-swizzled ----
#pragma unroll
  for (int it = 0; it < 4; ++it) {
    int i = (wid * 4 + it) * 64 + lane;              // LDS chunk index
    int s = i >> 3, cp = i & 7, c = cp ^ (s & 7);
    gload_lds16(Kb + (wtok + s) * 512 + hc + c * 8, &Kl[(size_t)((wid * 4 + it) * 64) * 8]);
  }
  // ---- stage V transposed + swizzled (reg scatter) ----
#pragma unroll
  for (int it = 0; it < 4; ++it) {
    int j = tid + it * 512;
    int s = j >> 3, d0 = (j & 7) * 8;
    i4_t v = *(const i4_t*)(Vb + (wtok + s) * 512 + hc + d0);
    const __bf16* ve = (const __bf16*)&v;
#pragma unroll
    for (int jj = 0; jj < 8; ++jj) {
      int d = d0 + jj;
      Vt[d * 256 + ((((s >> 3) ^ (d & 7)) << 3) | (s & 7))] = ve[jj];
    }
  }
  __syncthreads();

  __bf16* Pw = &Pl[wid][0];
  const float CLOG2E = 0.18033688011112043f;        // 0.125 * log2(e)

  for (int qt = 0; qt < 2; ++qt) {
    int qbase = wid * 32 + qt * 16;
    // Q fragments (B-frag: row q = l15, k-chunk kq*8 + k2*32), from L2
    bf8_t qf[2];
#pragma unroll
    for (int k2 = 0; k2 < 2; ++k2)
      qf[k2] = *(const bf8_t*)(Qb + (wtok + qbase + l15) * 512 + hc + k2 * 32 + kq * 8);

    // ---- QK^T swapped: sacc[st][r] = S^T[s = st*16+kq*4+r][q = l15] ----
    f4_t sacc[16];
#pragma unroll
    for (int st = 0; st < 16; ++st) {
      f4_t z = {0.f, 0.f, 0.f, 0.f};
      int s = st * 16 + l15;
#pragma unroll
      for (int k2 = 0; k2 < 2; ++k2) {
        int c = (k2 * 4 + kq) ^ (s & 7);
        bf8_t kf = *(const bf8_t*)&Kl[(s * 8 + c) * 8];
        z = __builtin_amdgcn_mfma_f32_16x16x32_bf16(kf, qf[k2], z, 0, 0, 0);
      }
      sacc[st] = z;
    }

    // ---- full-row softmax, in-lane ----
    float mx = -3.0e38f;
#pragma unroll
    for (int st = 0; st < 16; ++st) {
      f4_t u = sacc[st] * CLOG2E;
      sacc[st] = u;
      mx = fmaxf(mx, fmaxf(fmaxf(u[0], u[1]), fmaxf(u[2], u[3])));
    }
    mx = fmaxf(mx, __shfl_xor(mx, 16, 64));
    mx = fmaxf(mx, __shfl_xor(mx, 32, 64));
    float L = 0.f;
#pragma unroll
    for (int st = 0; st < 16; ++st) {
#pragma unroll
      for (int r = 0; r < 4; ++r) {
        float p = __builtin_amdgcn_exp2f(sacc[st][r] - mx);
        sacc[st][r] = p;
        L += p;
      }
    }
    L += __shfl_xor(L, 16, 64);
    L += __shfl_xor(L, 32, 64);
    float rinv = 1.0f / L;

    // ---- write normalized P (bf16) to per-wave swizzled LDS ----
#pragma unroll
    for (int st = 0; st < 16; ++st) {
      union { __bf16 h[4]; uint2 u; } tt;
#pragma unroll
      for (int r = 0; r < 4; ++r) tt.h[r] = (__bf16)(sacc[st][r] * rinv);
      int cp = (4 * st + kq) ^ l15;
      *(uint2*)&Pw[l15 * 256 + cp * 4] = tt.u;
    }

    // ---- PV: O[q][d] = P @ V ----
    f4_t oacc[4];
#pragma unroll
    for (int dn = 0; dn < 4; ++dn) oacc[dn] = f4_t{0.f, 0.f, 0.f, 0.f};
#pragma unroll
    for (int ks = 0; ks < 8; ++ks) {
      int c0 = 8 * ks + 2 * kq;
      uint2 pa0 = *(const uint2*)&Pw[l15 * 256 + ((c0 ^ l15) * 4)];
      uint2 pa1 = *(const uint2*)&Pw[l15 * 256 + (((c0 + 1) ^ l15) * 4)];
      union { uint u[4]; bf8_t v; } pu;
      pu.u[0] = pa0.x; pu.u[1] = pa0.y; pu.u[2] = pa1.x; pu.u[3] = pa1.y;
#pragma unroll
      for (int dn = 0; dn < 4; ++dn) {
        int d = dn * 16 + l15;
        bf8_t vf = *(const bf8_t*)&Vt[d * 256 + (((4 * ks + kq) ^ (d & 7)) << 3)];
        oacc[dn] = __builtin_amdgcn_mfma_f32_16x16x32_bf16(pu.v, vf, oacc[dn], 0, 0, 0);
      }
    }

    // ---- write O (already normalized) ----
#pragma unroll
    for (int dn = 0; dn < 4; ++dn)
#pragma unroll
      for (int r = 0; r < 4; ++r) {
        size_t row = wtok + qbase + kq * 4 + r;
        AOb[row * 512 + hc + dn * 16 + l15] = (__bf16)oacc[dn][r];
      }
  }
}

extern "C" void kernel_launch(void* const* d_in, const int* in_sizes, int n_in,
                              void* d_out, int out_size, void* d_ws, size_t ws_size,
                              hipStream_t stream) {
  const float* x  = (const float*)d_in[0];
  const float* y  = (const float*)d_in[1];
  const float* Wq = (const float*)d_in[2];
  const float* bq = (const float*)d_in[3];
  const float* Wk = (const float*)d_in[4];
  const float* bk = (const float*)d_in[5];
  const float* Wv = (const float*)d_in[6];
  const float* bv = (const float*)d_in[7];
  const float* Wo = (const float*)d_in[8];
  const float* bo = (const float*)d_in[9];
  const float* W1 = (const float*)d_in[10];
  const float* b1 = (const float*)d_in[11];
  const float* W2 = (const float*)d_in[12];
  const float* b2 = (const float*)d_in[13];

  char* ws = (char*)d_ws;
  size_t off = 0;
  auto carve = [&](size_t bytes) -> void* {
    void* p = ws + off;
    off += (bytes + 255) & ~(size_t)255;
    return p;
  };
  __bf16* WqvT = (__bf16*)carve((size_t)1024 * 512 * 2);  // [Wq^T; Wv^T]
  __bf16* WkT  = (__bf16*)carve((size_t)512 * 512 * 2);
  __bf16* WoT  = (__bf16*)carve((size_t)512 * 512 * 2);
  __bf16* W1T  = (__bf16*)carve((size_t)2048 * 512 * 2);
  __bf16* W2T  = (__bf16*)carve((size_t)512 * 2048 * 2);
  int* srcoff = (int*)carve((size_t)NTOK * 4);
  int* outoff = (int*)carve((size_t)NTOK * 4);
  __bf16* Asrc = (__bf16*)carve((size_t)NTOK * 512 * 2);
  __bf16* Aoth = (__bf16*)carve((size_t)NTOK * 512 * 2);
  __bf16* Qb   = (__bf16*)carve((size_t)NTOK * 512 * 2);
  __bf16* Kb   = (__bf16*)carve((size_t)NTOK * 512 * 2);
  __bf16* Vb   = (__bf16*)carve((size_t)NTOK * 512 * 2);
  // MLP hidden: adaptive chunking to fit ws_size
  int nc = 1;
  while (nc < 4 && off + (size_t)(NTOK / nc) * 2048 * 2 > ws_size) nc *= 2;
  int rows = NTOK / nc;
  __bf16* Hb = (__bf16*)carve((size_t)rows * 2048 * 2);
  // aliases (lifetimes: producer of alias runs after last reader of original)
  __bf16* AOb   = Asrc;              // attention out  (Asrc dead after QV-GEMM)
  __bf16* toksb = Aoth;              // tokens bf16    (Aoth dead after K-GEMM)
  float*  toksf = (float*)Kb;        // tokens fp32, spans Kb+Vb (dead after attention)
  float*  dout  = (float*)d_out;

  dim3 tb(256);
  transpose_cast<<<dim3(512 / 32, 512 / 32), tb, 0, stream>>>(Wq, WqvT, 512, 512);
  transpose_cast<<<dim3(512 / 32, 512 / 32), tb, 0, stream>>>(Wv, WqvT + (size_t)512 * 512, 512, 512);
  transpose_cast<<<dim3(512 / 32, 512 / 32), tb, 0, stream>>>(Wk, WkT, 512, 512);
  transpose_cast<<<dim3(512 / 32, 512 / 32), tb, 0, stream>>>(Wo, WoT, 512, 512);
  transpose_cast<<<dim3(2048 / 32, 512 / 32), tb, 0, stream>>>(W1, W1T, 512, 2048);
  transpose_cast<<<dim3(512 / 32, 2048 / 32), tb, 0, stream>>>(W2, W2T, 2048, 512);

  pack_tokens<<<NTOK, 256, 0, stream>>>(x, y, Asrc, Aoth, srcoff, outoff);

  // fused Q+V projection (one pass over Asrc), K projection
  gemm_bt<4><<<dim3(NTOK / 128, 8), 256, 0, stream>>>(Asrc, WqvT, bq, bv, 512, 0, Qb, Vb, nullptr, nullptr, nullptr, nullptr, nullptr, nullptr, nullptr);
  gemm_bt<0><<<dim3(NTOK / 128, 4), 256, 0, stream>>>(Aoth, WkT, bk, nullptr, 512, 0, Kb, nullptr, nullptr, nullptr, nullptr, nullptr, nullptr, nullptr, nullptr);

  attn_kernel<<<160 * 8, 512, 0, stream>>>(Qb, Kb, Vb, AOb);

  gemm_bt<1><<<dim3(NTOK / 128, 4), 256, 0, stream>>>(AOb, WoT, bo, nullptr, 512, 0, toksb, nullptr, toksf, x, y, srcoff, nullptr, nullptr, nullptr);

  for (int c = 0; c < nc; ++c) {
    int r0 = c * rows;
    gemm_bt<2><<<dim3(rows / 128, 16), 256, 0, stream>>>(toksb + (size_t)r0 * 512, W1T, b1, nullptr, 512, r0, Hb, nullptr, nullptr, nullptr, nullptr, nullptr, nullptr, nullptr, nullptr);
    gemm_bt<3><<<dim3(rows / 128, 4), 256, 0, stream>>>(Hb, W2T, b2, nullptr, 2048, r0, nullptr, nullptr, nullptr, nullptr, nullptr, nullptr, outoff, toksf, dout);
  }
}